// Round 9
// baseline (289.651 us; speedup 1.0000x reference)
//
#include <hip/hip_runtime.h>

typedef unsigned short u16;
typedef __attribute__((ext_vector_type(4))) unsigned int u32x4;
typedef __attribute__((ext_vector_type(4))) float f32x4;
typedef __attribute__((ext_vector_type(8))) __bf16 bf16x8;

// Problem constants (fixed by the reference).
constexpr int NV    = 20000;
constexpr int ND    = 8;
constexpr int CH    = 16;
constexpr int NF    = 16;
constexpr int NVD   = NV * ND;        // 160000 rows of y_flat per batch
constexpr int NCHUNK = 36;            // 32 conv chunks + 4 center chunks (K=1152)
constexpr int TPB   = 313;            // tiles per batch (last tile has 32 valid rows)
constexpr int PREP_BLOCKS = 1250;
constexpr int K2_BLOCKS   = 576;
constexpr int MREC_BLOCKS = 5000;     // 1,280,000 threads, one (v,rd) each

// ws layout (bytes):
//   [0, 10,240,000)              y16  : bf16 [B][NVD][CH]
//   [10,240,000, 10,534,912)     k2c  : bf16 [36][128][32]
//   [10,534,912, 51,494,912)     mrec : u32  [NV][2][32][8]  packed meta records
//       record = {i0,i1,i2, bits(w0), bits(w1), bits(w2), pad, pad}; i=(c*8+a)*16
constexpr size_t Y16_OFF_B  = 0;
constexpr size_t K2C_OFF_B  = 10240000;
constexpr size_t MREC_OFF_B = 10534912;   // total ws needed = 51,494,912 B

__device__ __forceinline__ u16 f2bf(float x) {
    unsigned int u = __float_as_uint(x);
    unsigned int r = (u + 0x7fffu + ((u >> 16) & 1u)) >> 16;   // RNE
    return (u16)r;
}
__device__ __forceinline__ unsigned int pack2bf(float a, float b) {
    return (unsigned int)f2bf(a) | ((unsigned int)f2bf(b) << 16);
}

// ---------------- P: merged prep (y->y16) + k2c build + mrec prepass ----------------
__global__ __launch_bounds__(256) void prep_k2(const float* __restrict__ y,
                                               u16* __restrict__ y16,
                                               const float* __restrict__ kern,
                                               const float* __restrict__ ck,
                                               u16* __restrict__ k2c,
                                               const int* __restrict__ contrib,
                                               const int* __restrict__ angles,
                                               const float* __restrict__ wbary,
                                               unsigned* __restrict__ mrec) {
    int bid = blockIdx.x;
    if (bid < PREP_BLOCKS) {
        int tid = bid * 256 + threadIdx.x;          // [0, 320000)
        const float4* src = (const float4*)(y + (size_t)tid * 16);
        float4 v0 = src[0], v1 = src[1], v2 = src[2], v3 = src[3];
        u32x4 lo = {pack2bf(v0.x, v0.y), pack2bf(v0.z, v0.w), pack2bf(v1.x, v1.y), pack2bf(v1.z, v1.w)};
        u32x4 hi = {pack2bf(v2.x, v2.y), pack2bf(v2.z, v2.w), pack2bf(v3.x, v3.y), pack2bf(v3.z, v3.w)};
        u16* yd = y16 + (size_t)tid * 16;
        *(u32x4*)(yd)     = lo;
        *(u32x4*)(yd + 8) = hi;
    } else if (bid < PREP_BLOCKS + K2_BLOCKS) {
        int e = (bid - PREP_BLOCKS) * 256 + threadIdx.x;   // [0, 36*4096)
        int i = e & 4095;
        int kc = e >> 12;
        int n = i >> 5, kk = i & 31;
        int k = kc * 32 + kk;
        int w = n >> 4, f = n & 15;
        float val;
        if (k < 1024) {
            int r = k >> 7, dd = (k >> 4) & 7, c = k & 15;
            int d = (dd - w) & 7;
            val = kern[((r * 8 + d) * 16 + c) * 16 + f];
        } else {
            int ke = k - 1024;
            int d = ke >> 4, c = ke & 15;
            val = (d == w) ? ck[c * 16 + f] : 0.f;
        }
        k2c[e] = f2bf(val);
    } else {
        // mrec prepass: one thread per (v, rd); coalesced 12-B reads, 24-B record write
        int tid = (bid - (PREP_BLOCKS + K2_BLOCKS)) * 256 + threadIdx.x;  // [0, 1.28M)
        int v = tid >> 6, rd = tid & 63;
        int kc = rd >> 1, sp = rd & 1;
        const int*   cp = contrib + (size_t)tid * 3;
        const int*   ap = angles  + (size_t)tid * 3;
        const float* wp = wbary   + (size_t)tid * 3;
        u32x4 r0;
        r0[0] = (unsigned)(cp[0] * 128 + ap[0] * 16);
        r0[1] = (unsigned)(cp[1] * 128 + ap[1] * 16);
        r0[2] = (unsigned)(cp[2] * 128 + ap[2] * 16);
        r0[3] = __float_as_uint(wp[0]);
        float2 r1 = {wp[1], wp[2]};
        unsigned* dst = mrec + ((size_t)(v * 2 + sp) * 32 + kc) * 8;
        *(u32x4*)(dst)      = r0;
        *(float2*)(dst + 4) = r1;
    }
}

// ---------------- F: FUSED gather + barycentric + GEMM + bias/relu/max — BARRIER-FREE ----------------
// r8 lesson: 36 __syncthreads per item each drain vmcnt(0) -> the gather pipeline never
// ran deeper than one barrier interval. This version has ZERO LDS and ZERO barriers:
//   B fragments : direct per-lane 16B loads from k2c (L2/L1-resident; all waves same addrs)
//   meta        : direct per-lane loads of packed 32-B mrec records (2 loads/chunk)
//   gathers     : depth-3 named-register pipeline (rule #20), counted-vmcnt waits only
// No K-split; epilogue in-kernel; 632 blocks (2.47/CU) all co-resident at 4-block cap.
__global__ __launch_bounds__(256, 4) void fused_gather_gemm(const u16* __restrict__ y16,
                                                            const unsigned* __restrict__ mrec,
                                                            const u16* __restrict__ k2c,
                                                            const float* __restrict__ bias,
                                                            float* __restrict__ out) {
    const int bid = blockIdx.x;
    const int xcd = bid & 7;
    const int g   = xcd >> 2;                         // batch group (XCD 0-3 / 4-7)
    const int tile = (bid >> 3) * 4 + (xcd & 3);
    if (tile >= TPB) return;
    const int t = threadIdx.x;
    const int w = t >> 6, lane = t & 63;
    const int lrow = lane & 15, lq = lane >> 4;
    const int s_p = lq >> 1;                 // rd parity this lane owns
    const int h8  = (lq & 1) * 8;            // ch-half element offset
    const int rb  = tile * 64 + w * 16 + lrow;        // row within batch (may be >= NV)
    const int v_p = rb < NV ? rb : NV - 1;            // clamped vertex
    const u16* __restrict__ yb = y16 + (size_t)g * NVD * CH + h8;
    const unsigned* __restrict__ mb = mrec + (size_t)(v_p * 2 + s_p) * 256;  // 32 kc * 8
    const u16* __restrict__ kb = k2c + lrow * 32 + lq * 8;   // + kc*4096 + nt*512

    // pipeline state — ALL named (rule #20); slots A/B/C rotate with period 3
    u32x4 miA, miB, miC;          // meta: {i0,i1,i2,bits(w0)}
    float2 mwA, mwB, mwC;         // meta: {w1,w2}
    u32x4 gA0, gA1, gA2, gB0, gB1, gB2, gC0, gC1, gC2;
    float vA0, vA1, vA2, vB0, vB1, vB2, vC0, vC1, vC2;

    f32x4 acc[8];
    #pragma unroll
    for (int nt = 0; nt < 8; ++nt) acc[nt] = (f32x4){0.f, 0.f, 0.f, 0.f};

#define META_ISSUE(S, KC_) { mi##S = *(const u32x4*)(mb + (KC_) * 8);              \
                             mw##S = *(const float2*)(mb + (KC_) * 8 + 4); }

#define G_ISSUE(S, KC_) {                                                          \
    if ((KC_) < 32) {                                                              \
        g##S##0 = *(const u32x4*)(yb + mi##S[0]);                                  \
        g##S##1 = *(const u32x4*)(yb + mi##S[1]);                                  \
        g##S##2 = *(const u32x4*)(yb + mi##S[2]);                                  \
        v##S##0 = __uint_as_float(mi##S[3]);                                       \
        v##S##1 = mw##S.x; v##S##2 = mw##S.y;                                      \
    } else {                                                                       \
        g##S##0 = *(const u32x4*)(yb + (size_t)((unsigned)v_p * 128u +             \
                                      (unsigned)(2 * ((KC_) - 32) + s_p) * 16u));  \
    } }

#define COMBINE(S, KC_, A_) {                                                      \
    if ((KC_) < 32) {                                                              \
        float ac_[8];                                                              \
        _Pragma("unroll") for (int x_ = 0; x_ < 8; ++x_) ac_[x_] = 0.f;            \
        _Pragma("unroll")                                                          \
        for (int q_ = 0; q_ < 4; ++q_) {                                           \
            unsigned u0_ = g##S##0[q_], u1_ = g##S##1[q_], u2_ = g##S##2[q_];      \
            ac_[2 * q_]     += v##S##0 * __uint_as_float(u0_ << 16);               \
            ac_[2 * q_ + 1] += v##S##0 * __uint_as_float(u0_ & 0xffff0000u);       \
            ac_[2 * q_]     += v##S##1 * __uint_as_float(u1_ << 16);               \
            ac_[2 * q_ + 1] += v##S##1 * __uint_as_float(u1_ & 0xffff0000u);       \
            ac_[2 * q_]     += v##S##2 * __uint_as_float(u2_ << 16);               \
            ac_[2 * q_ + 1] += v##S##2 * __uint_as_float(u2_ & 0xffff0000u);       \
        }                                                                          \
        u32x4 o_;                                                                  \
        _Pragma("unroll") for (int q_ = 0; q_ < 4; ++q_)                           \
            o_[q_] = pack2bf(ac_[2 * q_], ac_[2 * q_ + 1]);                        \
        A_ = *(bf16x8*)&o_;                                                        \
    } else { u32x4 o_ = g##S##0; A_ = *(bf16x8*)&o_; } }

// Per-chunk body: COMBINE(kc) -> refill gather slot for kc+3 (meta slot S holds kc+3)
// -> refill meta slot for kc+6 -> 8 direct B loads + 8 MFMA (two groups of 4).
#define CHUNK(S, KC_) {                                                            \
    bf16x8 av_;                                                                    \
    COMBINE(S, KC_, av_);                                                          \
    if ((KC_) + 3 < NCHUNK) G_ISSUE(S, (KC_) + 3)                                  \
    if ((KC_) + 6 < 32)     META_ISSUE(S, (KC_) + 6)                               \
    const u16* kb_ = kb + (size_t)(KC_) * 4096;                                    \
    {   bf16x8 b0_ = *(const bf16x8*)(kb_);                                        \
        bf16x8 b1_ = *(const bf16x8*)(kb_ + 512);                                  \
        bf16x8 b2_ = *(const bf16x8*)(kb_ + 1024);                                 \
        bf16x8 b3_ = *(const bf16x8*)(kb_ + 1536);                                 \
        acc[0] = __builtin_amdgcn_mfma_f32_16x16x32_bf16(av_, b0_, acc[0], 0, 0, 0); \
        acc[1] = __builtin_amdgcn_mfma_f32_16x16x32_bf16(av_, b1_, acc[1], 0, 0, 0); \
        acc[2] = __builtin_amdgcn_mfma_f32_16x16x32_bf16(av_, b2_, acc[2], 0, 0, 0); \
        acc[3] = __builtin_amdgcn_mfma_f32_16x16x32_bf16(av_, b3_, acc[3], 0, 0, 0); \
    }                                                                              \
    {   bf16x8 b4_ = *(const bf16x8*)(kb_ + 2048);                                 \
        bf16x8 b5_ = *(const bf16x8*)(kb_ + 2560);                                 \
        bf16x8 b6_ = *(const bf16x8*)(kb_ + 3072);                                 \
        bf16x8 b7_ = *(const bf16x8*)(kb_ + 3584);                                 \
        acc[4] = __builtin_amdgcn_mfma_f32_16x16x32_bf16(av_, b4_, acc[4], 0, 0, 0); \
        acc[5] = __builtin_amdgcn_mfma_f32_16x16x32_bf16(av_, b5_, acc[5], 0, 0, 0); \
        acc[6] = __builtin_amdgcn_mfma_f32_16x16x32_bf16(av_, b6_, acc[6], 0, 0, 0); \
        acc[7] = __builtin_amdgcn_mfma_f32_16x16x32_bf16(av_, b7_, acc[7], 0, 0, 0); \
    } }

    // ---- prologue: meta lead 6, gather lead 3 ----
    META_ISSUE(A, 0)
    META_ISSUE(B, 1)
    META_ISSUE(C, 2)
    G_ISSUE(A, 0) META_ISSUE(A, 3)
    G_ISSUE(B, 1) META_ISSUE(B, 4)
    G_ISSUE(C, 2) META_ISSUE(C, 5)

    // ---- main loop: 12 x 3 chunks; slot = kc % 3; no barriers anywhere ----
    for (int p = 0; p < 12; ++p) {
        const int base = 3 * p;
        CHUNK(A, base)
        CHUNK(B, base + 1)
        CHUNK(C, base + 2)
    }
#undef META_ISSUE
#undef G_ISSUE
#undef COMBINE
#undef CHUNK

    // epilogue: +bias, relu, max over w (= max over nt), exclusive store; guard tail rows
    if (tile * 64 + w * 16 + lq * 4 < NV) {
        const float bb = bias[lrow];
        const int m0 = g * NV + tile * 64 + w * 16 + lq * 4;
        #pragma unroll
        for (int reg = 0; reg < 4; ++reg) {
            float m = 0.f;   // relu floor
            #pragma unroll
            for (int nt = 0; nt < 8; ++nt) m = fmaxf(m, acc[nt][reg] + bb);
            out[(size_t)(m0 + reg) * NF + lrow] = m;
        }
    }
}

extern "C" void kernel_launch(void* const* d_in, const int* in_sizes, int n_in,
                              void* d_out, int out_size, void* d_ws, size_t ws_size,
                              hipStream_t stream) {
    const float* y      = (const float*)d_in[0];
    const int*   contrib= (const int*)d_in[1];
    const float* wbary  = (const float*)d_in[2];
    const int*   angles = (const int*)d_in[3];
    const float* kern   = (const float*)d_in[4];
    const float* ck     = (const float*)d_in[5];
    const float* bias   = (const float*)d_in[6];
    float* out = (float*)d_out;

    u16*      y16  = (u16*)((char*)d_ws + Y16_OFF_B);
    u16*      k2c  = (u16*)((char*)d_ws + K2C_OFF_B);
    unsigned* mrec = (unsigned*)((char*)d_ws + MREC_OFF_B);  // needs ws >= 51,494,912 B

    prep_k2<<<PREP_BLOCKS + K2_BLOCKS + MREC_BLOCKS, 256, 0, stream>>>(
        y, y16, kern, ck, k2c, contrib, angles, wbary, mrec);          // 6826 blocks
    fused_gather_gemm<<<((TPB + 3) / 4) * 8, 256, 0, stream>>>(        // 632 blocks
        y16, mrec, k2c, bias, out);
}